// Round 12
// baseline (38.275 us; speedup 1.0000x reference)
//
#include <hip/hip_runtime.h>

// HighOrderActivationB, round 11: bf16 LDS params -> halve LDS gather cost.
// r7 fixed TA saturation (67->36us). r6/r9/r10 (MLP/occupancy/store-density)
// all null at ~36.5us. Model: co-limiters are HBM writes (~19us/CU-share) and
// LDS gathers (6x b128 x conflicts ~ 19-23us/CU). This round halves the LDS
// side: param rows staged as bf16 (8 outs = 16B = ONE ds_read_b128 per term).
// Error bound: m2*max|P|*2^-9 ~ 0.05 << 0.275 threshold.

#define B_BATCH 4096
#define N_GROUPS 1024
#define N_TERMS 27
#define OUT_DIM 8
#define GC 16            // groups per block
#define BC 256           // batch rows per block
#define ROWD 116         // LDS row stride in dwords (464B: 16B-aligned, 8 bank-start spread)
#define NPAIR 108        // data dwords per row (216 bf16)

typedef float floatx4 __attribute__((ext_vector_type(4)));

__device__ __forceinline__ unsigned int bf16_rne_lo(unsigned int u) {
    return (u + 0x7fffu + ((u >> 16) & 1u)) >> 16;            // bf16 in low 16
}
__device__ __forceinline__ unsigned int bf16_rne_hi(unsigned int u) {
    return (u + 0x7fffu + ((u >> 16) & 1u)) & 0xffff0000u;    // bf16 in high 16
}

__global__ __launch_bounds__(256)
void hoa_kernel(const float* __restrict__ X,
                const float* __restrict__ P,
                float* __restrict__ out) {
    __shared__ unsigned int ldsb[GC * ROWD];   // 7424 B

    const int tid = threadIdx.x;
    const int g0 = blockIdx.x * GC;
    const int b0 = blockIdx.y * BC;

    // ---- stage GC param rows as bf16 pairs (dense float2 reads) ----
    for (int i = tid; i < GC * NPAIR; i += 256) {
        const int r = i / NPAIR;
        const int c = i - r * NPAIR;
        const float* src = P + (size_t)(g0 + r) * (N_TERMS * OUT_DIM) + 2 * c;
        const unsigned int lo = bf16_rne_lo(__float_as_uint(src[0]));
        const unsigned int hi = bf16_rne_hi(__float_as_uint(src[1]));
        ldsb[r * ROWD + c] = lo | hi;
    }
    __syncthreads();

    const int g_local = tid & (GC - 1);
    const int b_slot  = tid >> 4;            // 0..15
    const unsigned int* lg = ldsb + g_local * ROWD;
    const int g = g0 + g_local;

    #pragma unroll 4
    for (int it = 0; it < BC / 16; ++it) {   // 16 iterations
        const int b = b0 + b_slot + it * 16;

        // dense X read: 16 consecutive g x 4 b per wave -> 192B segments
        const float* xp = X + (size_t)b * (N_GROUPS * 3) + g * 3;
        const float A0 = xp[0];
        const float A1 = xp[1];
        const float A2 = xp[2];

        float m0 = fabsf(A0), m1 = fabsf(A1), m2 = fabsf(A2);
        int t0 = (A0 >= 0.0f) ? 1 : -1;
        int t1 = (A1 >= 0.0f) ? 3 : -3;
        int t2 = (A2 >= 0.0f) ? 9 : -9;

        // stable ascending 3-sort by magnitude (strict > = stable)
        if (m0 > m1) { float tm=m0; m0=m1; m1=tm; int tt=t0; t0=t1; t1=tt; }
        if (m1 > m2) { float tm=m1; m1=m2; m2=tm; int tt=t1; t1=t2; t2=tt; }
        if (m0 > m1) { float tm=m0; m0=m1; m1=tm; int tt=t0; t0=t1; t1=tt; }

        const float c0 = m0;
        const float c1 = m1 - m0;
        const float c2 = m2 - m1;

        const int i2 = 13 + t2;
        const int i1 = i2 + t1;
        const int i0 = i1 + t0;

        // ONE ds_read_b128 per term: 8 bf16 outs = 16B
        const uint4 q0 = *(const uint4*)(lg + i0 * 4);
        const uint4 q1 = *(const uint4*)(lg + i1 * 4);
        const uint4 q2 = *(const uint4*)(lg + i2 * 4);

        floatx4 oa, ob;
        oa.x = c0 * __uint_as_float(q0.x << 16)
             + c1 * __uint_as_float(q1.x << 16)
             + c2 * __uint_as_float(q2.x << 16);
        oa.y = c0 * __uint_as_float(q0.x & 0xffff0000u)
             + c1 * __uint_as_float(q1.x & 0xffff0000u)
             + c2 * __uint_as_float(q2.x & 0xffff0000u);
        oa.z = c0 * __uint_as_float(q0.y << 16)
             + c1 * __uint_as_float(q1.y << 16)
             + c2 * __uint_as_float(q2.y << 16);
        oa.w = c0 * __uint_as_float(q0.y & 0xffff0000u)
             + c1 * __uint_as_float(q1.y & 0xffff0000u)
             + c2 * __uint_as_float(q2.y & 0xffff0000u);
        ob.x = c0 * __uint_as_float(q0.z << 16)
             + c1 * __uint_as_float(q1.z << 16)
             + c2 * __uint_as_float(q2.z << 16);
        ob.y = c0 * __uint_as_float(q0.z & 0xffff0000u)
             + c1 * __uint_as_float(q1.z & 0xffff0000u)
             + c2 * __uint_as_float(q2.z & 0xffff0000u);
        ob.z = c0 * __uint_as_float(q0.w << 16)
             + c1 * __uint_as_float(q1.w << 16)
             + c2 * __uint_as_float(q2.w << 16);
        ob.w = c0 * __uint_as_float(q0.w & 0xffff0000u)
             + c1 * __uint_as_float(q1.w & 0xffff0000u)
             + c2 * __uint_as_float(q2.w & 0xffff0000u);

        // store: lanes 0..15 contiguous 512B per b-slot; L2 merges full lines
        floatx4* op = (floatx4*)(out + (size_t)b * (N_GROUPS * OUT_DIM) + g * OUT_DIM);
        op[0] = oa;
        op[1] = ob;
    }
}

extern "C" void kernel_launch(void* const* d_in, const int* in_sizes, int n_in,
                              void* d_out, int out_size, void* d_ws, size_t ws_size,
                              hipStream_t stream) {
    const float* X = (const float*)d_in[0];
    const float* P = (const float*)d_in[1];
    float* out = (float*)d_out;

    dim3 grid(N_GROUPS / GC, B_BATCH / BC);   // (64, 16) = 1024 blocks = 4/CU
    hoa_kernel<<<grid, 256, 0, stream>>>(X, P, out);
}

// Round 13
// 37.000 us; speedup vs baseline: 1.0345x; 1.0345x over previous
//
#include <hip/hip_runtime.h>

// HighOrderActivationB, round 12: pair-lane dense stores + NONTEMPORAL.
// Ledger: r7 fixed TA gathers (67->36). r6 MLP, r9 occupancy, r10 store
// density, r11 LDS-halving: all null -> LDS/issue/VALU/occupancy not limiting.
// Remaining theory: write stream allocating through L2 (write-once data)
// throttles the HBM write path. r10's pair-lane layout makes every store
// instruction cover dense contiguous 512B -> NT stores are safe (r5's 3.3x
// amplification was NT + 128B-strided lanes). fp32 params (r11 bf16 null).

#define B_BATCH 4096
#define N_GROUPS 1024
#define N_TERMS 27
#define OUT_DIM 8
#define GC 16           // groups per block
#define BC 256          // batch rows per block
#define ROW_STRIDE 220  // dwords: 16B-aligned rows, 8 distinct bank starts

typedef float floatx4 __attribute__((ext_vector_type(4)));

__global__ __launch_bounds__(256)
void hoa_kernel(const float* __restrict__ X,
                const float* __restrict__ P,
                float* __restrict__ out) {
    __shared__ float lds[GC * ROW_STRIDE];   // 14080 B

    const int tid = threadIdx.x;
    const int g0 = blockIdx.x * GC;
    const int b0 = blockIdx.y * BC;

    // ---- stage params for GC groups: 16 rows x 54 float4 ----
    {
        const floatx4* P4 = (const floatx4*)(P + (size_t)g0 * (N_TERMS * OUT_DIM));
        floatx4* L4 = (floatx4*)lds;
        for (int i = tid; i < GC * 54; i += 256) {
            const int r = i / 54;
            const int c = i - r * 54;
            L4[r * (ROW_STRIDE / 4) + c] = P4[i];
        }
    }
    __syncthreads();

    const int half    = tid & 1;             // which float4 of the 8 outputs
    const int g_local = (tid & 31) >> 1;     // 0..15
    const int b_slot  = tid >> 5;            // 0..7
    const float* lg = lds + g_local * ROW_STRIDE + half * 4;
    const int g = g0 + g_local;

    #pragma unroll 4
    for (int it = 0; it < BC / 8; ++it) {    // 32 iterations
        const int b = b0 + b_slot + it * 8;

        // X read: pair lanes duplicate the same 12B (coalescer dedups);
        // per instr: 2 b-rows x 192B dense segments.
        const float* xp = X + (size_t)b * (N_GROUPS * 3) + g * 3;
        const float A0 = xp[0];
        const float A1 = xp[1];
        const float A2 = xp[2];

        float m0 = fabsf(A0), m1 = fabsf(A1), m2 = fabsf(A2);
        int t0 = (A0 >= 0.0f) ? 1 : -1;
        int t1 = (A1 >= 0.0f) ? 3 : -3;
        int t2 = (A2 >= 0.0f) ? 9 : -9;

        // stable ascending 3-sort by magnitude (strict > = stable)
        if (m0 > m1) { float tm=m0; m0=m1; m1=tm; int tt=t0; t0=t1; t1=tt; }
        if (m1 > m2) { float tm=m1; m1=m2; m2=tm; int tt=t1; t1=t2; t2=tt; }
        if (m0 > m1) { float tm=m0; m0=m1; m1=tm; int tt=t0; t0=t1; t1=tt; }

        const float c0 = m0;
        const float c1 = m1 - m0;
        const float c2 = m2 - m1;

        const int i2 = 13 + t2;
        const int i1 = i2 + t1;
        const int i0 = i1 + t0;

        // LDS gathers: this lane's half only -> 3x ds_read_b128
        const floatx4 g0h = *(const floatx4*)(lg + i0 * OUT_DIM);
        const floatx4 g1h = *(const floatx4*)(lg + i1 * OUT_DIM);
        const floatx4 g2h = *(const floatx4*)(lg + i2 * OUT_DIM);

        const floatx4 o = c0 * g0h + c1 * g1h + c2 * g2h;

        // NT dense store: lanes 0..31 cover contiguous 512B (one b-row),
        // lanes 32..63 another -> full 64B sectors per instruction; NT
        // bypasses L2 allocate for this write-once stream.
        floatx4* op = (floatx4*)(out + (size_t)b * (N_GROUPS * OUT_DIM)
                                     + g * OUT_DIM + half * 4);
        __builtin_nontemporal_store(o, op);
    }
}

extern "C" void kernel_launch(void* const* d_in, const int* in_sizes, int n_in,
                              void* d_out, int out_size, void* d_ws, size_t ws_size,
                              hipStream_t stream) {
    const float* X = (const float*)d_in[0];
    const float* P = (const float*)d_in[1];
    float* out = (float*)d_out;

    dim3 grid(N_GROUPS / GC, B_BATCH / BC);   // (64, 16) = 1024 blocks = 4/CU
    hoa_kernel<<<grid, 256, 0, stream>>>(X, P, out);
}